// Round 15
// baseline (16.582 us; speedup 1.0000x reference)
//
#include <hip/hip_runtime.h>

// LogNorm moment-matching, v15: v14 (8-wave K-split) + A-frag preload-12
// issued BEFORE the X-phase. Discriminating A/B between:
//   H1 latency-serialized panel loads (VGPR=64 -> ~1 frag in flight,
//      12 x ~500cy cross-XCD L2-miss serial chain)  -> predict 10.5-12.5us
//   H2 L2-miss bandwidth wall (57 MB/rep @ ~3TB/s)   -> predict unchanged
// Preload = 48 VGPR on v14's 12-panel split (v8's failure was 96 VGPR on
// the 24-panel geometry -> pressure cliff; not a preload refutation).
//
//   e = exp(Z_mu + sigma^2/2); x1' = e/4; x2' = e*sigma/4        (C x G)
//   var_num'[s,g] = sum_{d<=c} sc * (w_sc w_sd corr_cd) * (x2'_c x2'_d)
//   Ssum'[s,g]    = W @ x1'; var = vn'/ss'^2 (scales cancel);
//   mu = log(ss') + log4 - var/2 ; sigma = sqrt(var)
//
// Panels: wave w takes p = i*8 + w, i in [0,12); dh = (i>=8) compile-time.
// MFMA 16x16x32_f16, layout as verified v2-v14.

#define S_STATES 16
#define C_TYPES  64
#define G_GENES  20000
#define OUT_HALF (S_STATES * G_GENES)
#define NPAIR    96
#define PER_WAVE 12

typedef _Float16 f16x2 __attribute__((ext_vector_type(2)));
typedef _Float16 f16x8 __attribute__((ext_vector_type(8)));
typedef float    f32x4 __attribute__((ext_vector_type(4)));

union Frag8 { f16x2 p[4]; f16x8 v; uint4 u; _Float16 h[8]; };

// ---- Kernel P: frag-ordered f16 A panels (1 KB each; 98 KB total) ----
__global__ __launch_bounds__(64)
void build_A(const float* __restrict__ corr, const float* __restrict__ w,
             unsigned short* __restrict__ cwA)
{
    const int p    = blockIdx.x;          // 0..97
    const int lane = threadIdx.x;
    const int gl   = lane & 15;           // state (A row)
    const int q    = lane >> 4;
    Frag8 v;
    if (p < NPAIR) {
        const int dh = (p >= 64);
        const int c  = dh ? p - 32 : p;
        const int d0 = dh * 32 + q * 8;
        const float wc = w[gl * C_TYPES + c];
        const float4 c0 = *(const float4*)(corr + c * C_TYPES + d0);
        const float4 c1 = *(const float4*)(corr + c * C_TYPES + d0 + 4);
        const float4 w0 = *(const float4*)(w + gl * C_TYPES + d0);
        const float4 w1 = *(const float4*)(w + gl * C_TYPES + d0 + 4);
        const float cv[8] = {c0.x,c0.y,c0.z,c0.w,c1.x,c1.y,c1.z,c1.w};
        const float wv[8] = {w0.x,w0.y,w0.z,w0.w,w1.x,w1.y,w1.z,w1.w};
#pragma unroll
        for (int j = 0; j < 8; ++j) {
            const int d = d0 + j;
            const float sc = (d < c) ? 2.0f : (d == c ? 1.0f : 0.0f);
            v.h[j] = (_Float16)(sc * cv[j] * wc * wv[j]);
        }
    } else {                               // W panels for the Ssum GEMM
        const int k0 = (p - NPAIR) * 32 + q * 8;
        const float4 w0 = *(const float4*)(w + gl * C_TYPES + k0);
        const float4 w1 = *(const float4*)(w + gl * C_TYPES + k0 + 4);
        const float wv[8] = {w0.x,w0.y,w0.z,w0.w,w1.x,w1.y,w1.z,w1.w};
#pragma unroll
        for (int j = 0; j < 8; ++j) v.h[j] = (_Float16)wv[j];
    }
    *(uint4*)(cwA + (p << 9) + lane * 8) = v.u;
}

// ---- Kernel M: main (512 thr = 8 waves, 32 genes/block) ----
__global__ __launch_bounds__(512, 4)
void lognorm_main(const float* __restrict__ Z_mu,
                  const float* __restrict__ Z_sigma,
                  const unsigned short* __restrict__ cwA,
                  float* __restrict__ out)
{
    __shared__ f16x2 x2pT[32][35];       // [gene][d-pair]
    __shared__ f16x2 x1pT[32][35];
    __shared__ f16x2 x2tp[C_TYPES][21];  // [c][(g,g+16) pair]; broadcast
    __shared__ float accs[8][S_STATES][33];
    __shared__ float ssum_s[S_STATES][33];

    const int gt    = blockIdx.x;        // 0..624, 32 genes (exact)
    const int tid   = threadIdx.x;       // 0..511
    const int w     = tid >> 6;          // wave 0..7 = K-interleave slot
    const int lane  = tid & 63;
    const int gl    = lane & 15;
    const int q     = lane >> 4;
    const int gbase = gt * 32;

    // ---- A-frag preload: FIRST instructions (12 x b128 = 48 VGPR);
    //      latency hides under Z loads + exp + barrier ----
    Frag8 afr[PER_WAVE];
    {
        const unsigned short* Abase = cwA + (w << 9) + lane * 8;
#pragma unroll
        for (int i = 0; i < PER_WAVE; ++i)
            afr[i].u = *(const uint4*)(Abase + (i << 12));
    }
    Frag8 wf0, wf1;
    if (w < 2) {                         // Ssum W panels (waves 0,1)
        wf0.u = *(const uint4*)(cwA + ((NPAIR + 0) << 9) + lane * 8);
        wf1.u = *(const uint4*)(cwA + ((NPAIR + 1) << 9) + lane * 8);
    }

    // ---- X-phase: thread -> rows 2dp,2dp+1 ; genes gq, gq+16 ----
    {
        const int dp = tid >> 4;         // 0..31
        const int gq = tid & 15;         // 0..15
        const float* zm = Z_mu    + (2*dp) * G_GENES + gbase + gq;
        const float* zs = Z_sigma + (2*dp) * G_GENES + gbase + gq;
        const float m00 = zm[0], m01 = zm[16];
        const float m10 = zm[G_GENES], m11 = zm[G_GENES + 16];
        const float s00 = zs[0], s01 = zs[16];
        const float s10 = zs[G_GENES], s11 = zs[G_GENES + 16];
        const float e00 = __expf(fmaf(0.5f*s00, s00, m00)) * 0.25f;
        const float e01 = __expf(fmaf(0.5f*s01, s01, m01)) * 0.25f;
        const float e10 = __expf(fmaf(0.5f*s10, s10, m10)) * 0.25f;
        const float e11 = __expf(fmaf(0.5f*s11, s11, m11)) * 0.25f;
        const float x200 = e00*s00, x201 = e01*s01;
        const float x210 = e10*s10, x211 = e11*s11;
        f16x2 a;
        a.x = (_Float16)x200; a.y = (_Float16)x210; x2pT[gq][dp]      = a;
        a.x = (_Float16)x201; a.y = (_Float16)x211; x2pT[gq + 16][dp] = a;
        a.x = (_Float16)e00;  a.y = (_Float16)e10;  x1pT[gq][dp]      = a;
        a.x = (_Float16)e01;  a.y = (_Float16)e11;  x1pT[gq + 16][dp] = a;
        a.x = (_Float16)x200; a.y = (_Float16)x201; x2tp[2*dp][gq]    = a;
        a.x = (_Float16)x210; a.y = (_Float16)x211; x2tp[2*dp+1][gq]  = a;
    }
    __syncthreads();

    // ---- B sources: xh (16 reads, reused 6x), xct (12 broadcast) ----
    f16x2 xh[2][4][2];                   // [dh][jp][t]
#pragma unroll
    for (int dh = 0; dh < 2; ++dh)
#pragma unroll
        for (int t = 0; t < 2; ++t)
#pragma unroll
            for (int jp = 0; jp < 4; ++jp)
                xh[dh][jp][t] = x2pT[gl + 16*t][dh*16 + q*4 + jp];

    f16x2 xct[PER_WAVE];
#pragma unroll
    for (int i = 0; i < PER_WAVE; ++i) {
        const int c = i*8 + w - ((i >= 8) ? 32 : 0);
        xct[i] = x2tp[c][gl];
    }

    // ---- K-loop: 12 x {8 pk_mul, 2 MFMA}; pure reg/LDS, no VMEM ----
    f32x4 acc0a = {0.f,0.f,0.f,0.f}, acc0b = {0.f,0.f,0.f,0.f};
    f32x4 acc1a = {0.f,0.f,0.f,0.f}, acc1b = {0.f,0.f,0.f,0.f};
#pragma unroll
    for (int i = 0; i < PER_WAVE; ++i) {
        const int dh = (i >= 8) ? 1 : 0;
        Frag8 b0, b1;
#pragma unroll
        for (int jp = 0; jp < 4; ++jp) {
            f16x2 s0; s0.x = xct[i].x; s0.y = xct[i].x;
            f16x2 s1; s1.x = xct[i].y; s1.y = xct[i].y;
            b0.p[jp] = s0 * xh[dh][jp][0];
            b1.p[jp] = s1 * xh[dh][jp][1];
        }
        if (i & 1) {
            acc0b = __builtin_amdgcn_mfma_f32_16x16x32_f16(afr[i].v, b0.v, acc0b, 0, 0, 0);
            acc1b = __builtin_amdgcn_mfma_f32_16x16x32_f16(afr[i].v, b1.v, acc1b, 0, 0, 0);
        } else {
            acc0a = __builtin_amdgcn_mfma_f32_16x16x32_f16(afr[i].v, b0.v, acc0a, 0, 0, 0);
            acc1a = __builtin_amdgcn_mfma_f32_16x16x32_f16(afr[i].v, b1.v, acc1a, 0, 0, 0);
        }
    }
    const f32x4 acc0 = acc0a + acc0b;
    const f32x4 acc1 = acc1a + acc1b;
#pragma unroll
    for (int r = 0; r < 4; ++r) {
        accs[w][q*4 + r][gl]      = acc0[r];
        accs[w][q*4 + r][gl + 16] = acc1[r];
    }

    // ---- Ssum GEMM: waves 0,1 -> gene subtiles 0,1 ----
    if (w < 2) {
        Frag8 x1f[2];
#pragma unroll
        for (int kk = 0; kk < 2; ++kk)
#pragma unroll
            for (int jp = 0; jp < 4; ++jp)
                x1f[kk].p[jp] = x1pT[gl + 16*w][kk*16 + q*4 + jp];
        f32x4 sa = {0.f,0.f,0.f,0.f};
        sa = __builtin_amdgcn_mfma_f32_16x16x32_f16(wf0.v, x1f[0].v, sa, 0, 0, 0);
        sa = __builtin_amdgcn_mfma_f32_16x16x32_f16(wf1.v, x1f[1].v, sa, 0, 0, 0);
#pragma unroll
        for (int r = 0; r < 4; ++r) ssum_s[q*4 + r][gl + 16*w] = sa[r];
    }
    __syncthreads();

    // ---- epilogue: thread -> (s = tid>>5, gene gx = tid&31) ----
    const int s  = tid >> 5;
    const int gx = tid & 31;
    float vn = 0.f;
#pragma unroll
    for (int k = 0; k < 8; ++k) vn += accs[k][s][gx];
    const float ss   = ssum_s[s][gx];                 // = Ssum/4
    const float rvar = fmaxf(vn, 0.f) / (ss * ss);    // scale cancels
    out[s * G_GENES + gbase + gx] =
        __logf(ss) + 1.3862943611f - 0.5f * rvar;     // + log 4
    out[OUT_HALF + s * G_GENES + gbase + gx] = sqrtf(rvar);
}

extern "C" void kernel_launch(void* const* d_in, const int* in_sizes, int n_in,
                              void* d_out, int out_size, void* d_ws, size_t ws_size,
                              hipStream_t stream) {
    const float* Z_mu      = (const float*)d_in[0];
    const float* Z_sigma   = (const float*)d_in[1];
    const float* corr      = (const float*)d_in[2];
    const float* cell_prob = (const float*)d_in[3];
    float* out = (float*)d_out;
    unsigned short* cwA = (unsigned short*)d_ws;   // 98 KB frag-ordered f16 A

    build_A<<<dim3(NPAIR + 2), dim3(64), 0, stream>>>(corr, cell_prob, cwA);

    const int gtiles = G_GENES / 32;               // 625, exact
    lognorm_main<<<dim3(gtiles), dim3(512), 0, stream>>>(
        Z_mu, Z_sigma, cwA, out);
}